// Round 18
// baseline (182.637 us; speedup 1.0000x reference)
//
#include <hip/hip_runtime.h>

// Sinkhorn (dustbin-augmented) v18: TWO batches interleaved in one block's
// iteration loop. Mechanism: the 40 barrier-locked phases/batch are the
// measured bound (no pipe >30% busy); two independent batches per phase
// halve the per-batch serial cost (4 indep MFMA chains, barriers amortized,
// grid 256 blocks = one round). Enabler: fp8 fragments (validated v14..v16,
// absmax 0.125) -> 4 fragment sets = 64 VGPRs = v9's proven budget.
// Staging: v17's f16 tile + gather (proven), fragments converted to fp8 ONCE
// at gather via HW v_cvt_pk_fp8_f32 (sw fallback = v14's validated encoder).
// Epilogue: v15's validated fp8-fragment-decode (esT dead after gathers).
//
// Scaled recursion per batch (A = 2^{alpha*log2e}, Cs = 2^8/A; fp8 carries
// es, 16*EU, 16*EV; accs 16x true, recovered via tdv16/tdu16):
//   EU_i  = 1/(sum_j es_ij*EV_j + A*evd),   eud = Cs/(sum EV + evd)
//   EV_j  = 1/(sum_i es_ij*EU_i + A*eud),   evd' = Cs/(sum EU + eud)
//   Z = (log2 es + log2 EU + log2 EV)*ln2   (dustbins use alpha2)
//
// Maps (proven v8..v17): wave w (0..15), lane l = l15 + 16g:
//   esA[s] byte j = es[16w+l15][32s+8g+j];  esB[s] byte j = es[32s+8g+j][16w+l15]
// C/D: col=lane&15, row=(lane>>4)*4+reg (HW-measured, dtype-independent).

typedef _Float16 half8 __attribute__((ext_vector_type(8)));
typedef float floatx4 __attribute__((ext_vector_type(4)));
typedef unsigned int uint2v __attribute__((ext_vector_type(2)));

constexpr float L2E = 1.4426950408889634f;
constexpr float LN2 = 0.6931471805599453f;

__device__ __forceinline__ float flog2(float x) { return __builtin_amdgcn_logf(x); }
__device__ __forceinline__ float fexp2(float x) { return __builtin_amdgcn_exp2f(x); }

__device__ __forceinline__ float rcp_nr(float d) {
    float r = __builtin_amdgcn_rcpf(d);
    return r * fmaf(-d, r, 2.0f);
}

template <int CTRL>
__device__ __forceinline__ float dpp_add(float x) {
    int y = __builtin_amdgcn_update_dpp(0, __builtin_bit_cast(int, x), CTRL, 0xF, 0xF, true);
    return x + __builtin_bit_cast(float, y);
}
__device__ __forceinline__ float reduce16(float x) {
    x = dpp_add<0xB1>(x); x = dpp_add<0x4E>(x);
    x = dpp_add<0x124>(x); x = dpp_add<0x128>(x);
    return x;
}
__device__ __forceinline__ float xor16_add(float x) {
    int y = __builtin_amdgcn_ds_swizzle(__builtin_bit_cast(int, x), 0x401F);
    return x + __builtin_bit_cast(float, y);
}

// f32 -> OCP e4m3fn (x>=0), validated v14..v16 (software fallback)
__device__ __forceinline__ unsigned f32_to_e4m3(float x) {
    if (!(x > 0.0f)) return 0u;
    if (x < 0.015625f) return (unsigned)(int)fmaf(x, 512.0f, 0.5f);
    unsigned u = __builtin_bit_cast(unsigned, x);
    unsigned r = u + 0x80000u;
    int e2 = (int)((r >> 23) & 255u) - 127;
    if (e2 > 8) return 0x7Eu;
    unsigned b = (unsigned)(((e2 + 7) << 3) | ((r >> 20) & 7u));
    if (b >= 0x7Fu) b = 0x7Eu;
    return b;
}
__device__ __forceinline__ float dec_e4m3(unsigned b) {
    unsigned e = (b >> 3) & 15u, m = b & 7u;
    if (e == 0) return (float)m * 0.001953125f;
    return __builtin_bit_cast(float, ((e + 120u) << 23) | (m << 20));
}

// 8 f16 -> 8 fp8 bytes (one long). HW pack if available.
__device__ __forceinline__ long h8_to_fp8(half8 h) {
    unsigned lo, hi;
#if __has_builtin(__builtin_amdgcn_cvt_pk_fp8_f32)
    lo = (unsigned)__builtin_amdgcn_cvt_pk_fp8_f32((float)h[0], (float)h[1], 0, false);
    lo = (unsigned)__builtin_amdgcn_cvt_pk_fp8_f32((float)h[2], (float)h[3], (int)lo, true);
    hi = (unsigned)__builtin_amdgcn_cvt_pk_fp8_f32((float)h[4], (float)h[5], 0, false);
    hi = (unsigned)__builtin_amdgcn_cvt_pk_fp8_f32((float)h[6], (float)h[7], (int)hi, true);
#else
    lo = 0; hi = 0;
    #pragma unroll
    for (int j = 0; j < 4; ++j) lo |= f32_to_e4m3((float)h[j]) << (j << 3);
    #pragma unroll
    for (int j = 0; j < 4; ++j) hi |= f32_to_e4m3((float)h[j + 4]) << (j << 3);
#endif
    uint2v p; p.x = lo; p.y = hi;
    return __builtin_bit_cast(long, p);
}
__device__ __forceinline__ unsigned f32_to_fp8b(float x) {
#if __has_builtin(__builtin_amdgcn_cvt_pk_fp8_f32)
    return (unsigned)__builtin_amdgcn_cvt_pk_fp8_f32(x, 0.0f, 0, false) & 255u;
#else
    return f32_to_e4m3(x);
#endif
}

// esT addressing (v17): col-major, stride 264 shorts, XOR swizzle + pad.
__device__ __forceinline__ int eidx(int col, int r) {
    return col * 264 + ((r ^ ((col & 7) << 3)) + (((col >> 3) & 1) << 3));
}

__global__ __launch_bounds__(1024)
__attribute__((amdgpu_waves_per_eu(4, 4)))
void sinkhorn_kernel(const float* __restrict__ scores,
                     const float* __restrict__ alpha_p,
                     const int* __restrict__ iters_p,
                     float* __restrict__ out, int B)
{
    const int t   = threadIdx.x;
    const int a   = t >> 5;
    const int bb  = t & 31;
    const int w   = t >> 6;
    const int l   = t & 63;
    const int g   = (t >> 4) & 3;
    const int l15 = t & 15;

    const int bat0 = blockIdx.x << 1;
    const bool haveB1 = (bat0 + 1) < B;
    const int bat1 = haveB1 ? (bat0 + 1) : bat0;

    const float alpha2 = alpha_p[0] * L2E;
    const float A  = fexp2(alpha2);
    const float Cs = fexp2(8.0f - alpha2);
    const int iters = iters_p[0];

    __shared__ __align__(16) unsigned short esT[256 * 264];   // 132 KB f16 staging
    __shared__ __align__(16) unsigned char  EV80[288], EV81[288];
    __shared__ __align__(16) unsigned char  EU80[288], EU81[288];
    __shared__ __align__(16) unsigned short EVh0[288], EVh1[288];
    __shared__ __align__(16) unsigned short EUh0[288], EUh1[288];
    __shared__ __align__(16) float wsU0[16], wsU1[16], wsV0[16], wsV1[16];

    // ---- v17 prologue (proven): one coalesced pass -> f16 tile ----
    auto stage = [&](int bat) {
        const float* sp = scores + ((size_t)bat << 16) + ((size_t)a << 11) + (bb << 2);
        half8 cp[8];
        #pragma unroll
        for (int r = 0; r < 8; ++r) {
            const float4 x0 = *reinterpret_cast<const float4*>(sp + (r << 8));
            const float4 x1 = *reinterpret_cast<const float4*>(sp + (r << 8) + 128);
            cp[0][r] = (_Float16)fexp2(x0.x * L2E);
            cp[1][r] = (_Float16)fexp2(x0.y * L2E);
            cp[2][r] = (_Float16)fexp2(x0.z * L2E);
            cp[3][r] = (_Float16)fexp2(x0.w * L2E);
            cp[4][r] = (_Float16)fexp2(x1.x * L2E);
            cp[5][r] = (_Float16)fexp2(x1.y * L2E);
            cp[6][r] = (_Float16)fexp2(x1.z * L2E);
            cp[7][r] = (_Float16)fexp2(x1.w * L2E);
        }
        #pragma unroll
        for (int ci = 0; ci < 8; ++ci) {
            const int col = (ci < 4) ? ((bb << 2) + ci) : (128 + (bb << 2) + ci - 4);
            *reinterpret_cast<half8*>(&esT[eidx(col, a << 3)]) = cp[ci];
        }
    };

    long esA0[8], esB0[8], esA1[8], esB1[8];
    auto gather = [&](long* eA, long* eB) {
        const int m16 = (w << 4) + l15;
        #pragma unroll
        for (int s = 0; s < 8; ++s) {
            half8 cp;
            #pragma unroll
            for (int j = 0; j < 8; ++j) {
                const int col = (s << 5) + (g << 3) + j;
                cp[j] = __builtin_bit_cast(_Float16, esT[eidx(col, m16)]);
            }
            eA[s] = h8_to_fp8(cp);
            asm volatile("" : "+v"(eA[s]));
        }
        #pragma unroll
        for (int s = 0; s < 8; ++s) {
            const half8 hb = *reinterpret_cast<const half8*>(
                &esT[eidx(m16, (s << 5) + (g << 3))]);
            eB[s] = h8_to_fp8(hb);
            asm volatile("" : "+v"(eB[s]));
        }
    };

    stage(bat0);
    __syncthreads();
    gather(esA0, esB0);
    __syncthreads();      // gather0 reads done before stage1 overwrites
    stage(bat1);
    if (t < 64) {
        reinterpret_cast<unsigned*>(EV80)[t] = 0x58585858u;   // fp8(16) = 16*EV0
        reinterpret_cast<unsigned*>(EV81)[t] = 0x58585858u;
    }
    if (t < 256) { EVh0[t] = 0x3C00; EVh1[t] = 0x3C00; }
    if (t < 16)  { wsV0[t] = 16.0f; wsV1[t] = 16.0f; }
    __syncthreads();
    gather(esA1, esB1);

    float evd0 = 1.0f, eud0 = 1.0f, evd1 = 1.0f, eud1 = 1.0f;

    for (int it = 0; it < iters; ++it) {
        // ---- scalars (both batches) ----
        float sv0 = evd0, sv1 = evd1;
        {
            const floatx4* p0 = reinterpret_cast<const floatx4*>(wsV0);
            const floatx4* p1 = reinterpret_cast<const floatx4*>(wsV1);
            floatx4 s0 = (p0[0] + p0[1]) + (p0[2] + p0[3]);
            floatx4 s1 = (p1[0] + p1[1]) + (p1[2] + p1[3]);
            sv0 += (s0[0] + s0[1]) + (s0[2] + s0[3]);
            sv1 += (s1[0] + s1[1]) + (s1[2] + s1[3]);
        }
        eud0 = Cs * rcp_nr(sv0);
        eud1 = Cs * rcp_nr(sv1);
        const float tdu0 = 16.0f * A * eud0, tdv0 = 16.0f * A * evd0;
        const float tdu1 = 16.0f * A * eud1, tdv1 = 16.0f * A * evd1;

        // ---- p-phase: 4 independent MFMA chains ----
        floatx4 c00 = {0,0,0,0}, c01 = {0,0,0,0}, c10 = {0,0,0,0}, c11 = {0,0,0,0};
        #pragma unroll
        for (int s = 0; s < 4; ++s) {
            const long b00 = *reinterpret_cast<const long*>(&EV80[((2*s) << 5) + (g << 3)]);
            const long b01 = *reinterpret_cast<const long*>(&EV80[((2*s+1) << 5) + (g << 3)]);
            const long b10 = *reinterpret_cast<const long*>(&EV81[((2*s) << 5) + (g << 3)]);
            const long b11 = *reinterpret_cast<const long*>(&EV81[((2*s+1) << 5) + (g << 3)]);
            c00 = __builtin_amdgcn_mfma_f32_16x16x32_fp8_fp8(esA0[2*s],   b00, c00, 0, 0, 0);
            c01 = __builtin_amdgcn_mfma_f32_16x16x32_fp8_fp8(esA0[2*s+1], b01, c01, 0, 0, 0);
            c10 = __builtin_amdgcn_mfma_f32_16x16x32_fp8_fp8(esA1[2*s],   b10, c10, 0, 0, 0);
            c11 = __builtin_amdgcn_mfma_f32_16x16x32_fp8_fp8(esA1[2*s+1], b11, c11, 0, 0, 0);
        }
        const floatx4 ap0 = c00 + c01;
        const floatx4 ap1 = c10 + c11;

        float E0[4], E1[4];
        #pragma unroll
        for (int i = 0; i < 4; ++i) {
            E0[i] = 16.0f * rcp_nr(ap0[i] + tdv0);
            E1[i] = 16.0f * rcp_nr(ap1[i] + tdv1);
        }
        if (l15 < 4) {  // rows 16w + 4g + l15
            const float v0 = (l15 & 2) ? ((l15 & 1) ? E0[3] : E0[2])
                                       : ((l15 & 1) ? E0[1] : E0[0]);
            const float v1 = (l15 & 2) ? ((l15 & 1) ? E1[3] : E1[2])
                                       : ((l15 & 1) ? E1[1] : E1[0]);
            const int i0 = (w << 4) + (g << 2) + l15;
            EUh0[i0] = __builtin_bit_cast(unsigned short, (_Float16)v0);
            EU80[i0] = (unsigned char)f32_to_fp8b(v0 * 16.0f);
            EUh1[i0] = __builtin_bit_cast(unsigned short, (_Float16)v1);
            EU81[i0] = (unsigned char)f32_to_fp8b(v1 * 16.0f);
        }
        float sU0 = (E0[0] + E0[1]) + (E0[2] + E0[3]);
        float sU1 = (E1[0] + E1[1]) + (E1[2] + E1[3]);
        sU0 = xor16_add(sU0); sU0 += __shfl_xor(sU0, 32, 64);
        sU1 = xor16_add(sU1); sU1 += __shfl_xor(sU1, 32, 64);
        if (l == 0) { wsU0[w] = sU0; wsU1[w] = sU1; }
        __syncthreads();

        // ---- scalars ----
        float su0 = eud0, su1 = eud1;
        {
            const floatx4* p0 = reinterpret_cast<const floatx4*>(wsU0);
            const floatx4* p1 = reinterpret_cast<const floatx4*>(wsU1);
            floatx4 s0 = (p0[0] + p0[1]) + (p0[2] + p0[3]);
            floatx4 s1 = (p1[0] + p1[1]) + (p1[2] + p1[3]);
            su0 += (s0[0] + s0[1]) + (s0[2] + s0[3]);
            su1 += (s1[0] + s1[1]) + (s1[2] + s1[3]);
        }
        evd0 = Cs * rcp_nr(su0);
        evd1 = Cs * rcp_nr(su1);

        // ---- q-phase: 4 independent chains ----
        floatx4 q00 = {0,0,0,0}, q01 = {0,0,0,0}, q10 = {0,0,0,0}, q11 = {0,0,0,0};
        #pragma unroll
        for (int s = 0; s < 4; ++s) {
            const long a00 = *reinterpret_cast<const long*>(&EU80[((2*s) << 5) + (g << 3)]);
            const long a01 = *reinterpret_cast<const long*>(&EU80[((2*s+1) << 5) + (g << 3)]);
            const long a10 = *reinterpret_cast<const long*>(&EU81[((2*s) << 5) + (g << 3)]);
            const long a11 = *reinterpret_cast<const long*>(&EU81[((2*s+1) << 5) + (g << 3)]);
            q00 = __builtin_amdgcn_mfma_f32_16x16x32_fp8_fp8(a00, esB0[2*s],   q00, 0, 0, 0);
            q01 = __builtin_amdgcn_mfma_f32_16x16x32_fp8_fp8(a01, esB0[2*s+1], q01, 0, 0, 0);
            q10 = __builtin_amdgcn_mfma_f32_16x16x32_fp8_fp8(a10, esB1[2*s],   q10, 0, 0, 0);
            q11 = __builtin_amdgcn_mfma_f32_16x16x32_fp8_fp8(a11, esB1[2*s+1], q11, 0, 0, 0);
        }
        const floatx4 aq0 = q00 + q01;
        const floatx4 aq1 = q10 + q11;

        const float EVv0 = 16.0f * rcp_nr(aq0[0] + tdu0);
        const float EVv1 = 16.0f * rcp_nr(aq1[0] + tdu1);
        if (l < 16) {
            EVh0[(w << 4) + l] = __builtin_bit_cast(unsigned short, (_Float16)EVv0);
            EV80[(w << 4) + l] = (unsigned char)f32_to_fp8b(EVv0 * 16.0f);
            EVh1[(w << 4) + l] = __builtin_bit_cast(unsigned short, (_Float16)EVv1);
            EV81[(w << 4) + l] = (unsigned char)f32_to_fp8b(EVv1 * 16.0f);
        }
        const float sV0 = reduce16(EVv0);
        const float sV1 = reduce16(EVv1);
        if (l == 0) { wsV0[w] = sV0; wsV1[w] = sV1; }
        __syncthreads();
    }

    // ---- epilogue (v15-validated fp8-fragment decode), per batch ----
    auto epi = [&](int bat, const long* eA, const unsigned short* EUh,
                   const unsigned short* EVh, float eud_, float evd_) {
        const int row = (w << 4) + l15;
        const float Ud = flog2(eud_);
        const float Vd = flog2(evd_);
        const float Up = flog2((float)__builtin_bit_cast(_Float16, EUh[row]));
        const size_t ob = (size_t)bat * 66049;
        float* rp = out + ob + (size_t)row * 257;
        #pragma unroll
        for (int s = 0; s < 8; ++s) {
            const uint2v pa = __builtin_bit_cast(uint2v, eA[s]);
            const half8 vh = *reinterpret_cast<const half8*>(&EVh[(s << 5) + (g << 3)]);
            const int c0 = (s << 5) + (g << 3);
            #pragma unroll
            for (int j = 0; j < 8; ++j) {
                const unsigned b = (pa[j >> 2] >> ((j & 3) * 8)) & 255u;
                rp[c0 + j] = (flog2(dec_e4m3(b)) + Up + flog2((float)vh[j])) * LN2;
            }
        }
        if (l < 16) rp[256] = (alpha2 + Up + Vd) * LN2;
        if (t < 257) {
            const float vp = (t < 256)
                ? flog2((float)__builtin_bit_cast(_Float16, EVh[t])) : Vd;
            out[ob + 65792 + t] = (alpha2 + Ud + vp) * LN2;
        }
    };

    epi(bat0, esA0, EUh0, EVh0, eud0, evd0);
    if (haveB1) epi(bat1, esA1, EUh1, EVh1, eud1, evd1);
}

extern "C" void kernel_launch(void* const* d_in, const int* in_sizes, int n_in,
                              void* d_out, int out_size, void* d_ws, size_t ws_size,
                              hipStream_t stream)
{
    const float* scores = (const float*)d_in[0];
    const float* alpha  = (const float*)d_in[1];
    const int*   iters  = (const int*)d_in[2];
    float* out = (float*)d_out;
    const int B = in_sizes[0] >> 16;
    hipLaunchKernelGGL(sinkhorn_kernel, dim3((B + 1) >> 1), dim3(1024), 0, stream,
                       scores, alpha, iters, out, B);
}

// Round 19
// 103.830 us; speedup vs baseline: 1.7590x; 1.7590x over previous
//
#include <hip/hip_runtime.h>

// Sinkhorn (dustbin-augmented), MFMA edition — FINAL (= v17, measured best:
// 102.8 us, absmax 0.0625).
//
// Structure: 1 block (1024 thr, 16 waves) per batch; f16 score tile staged
// once through a swizzled col-major LDS tile; A/B MFMA fragments pinned in
// registers (64 V + 64 A = exactly-full file at waves_per_eu(4,4)); both
// Sinkhorn matvecs on the matrix pipe via mfma_f32_16x16x32_f16 with a
// replicated operand; scalar state f32 with rcp+NR; 2 barriers/iteration;
// epilogue reads the tile once more.
//
// Falsified alternatives (18 rounds): LDS-conflict fixes (neutral — not on
// the critical path), intra-block staging pipelines (fence overhead), 2
// blocks/CU via fp8/no-tile (pack VALU + double-fetch + spill), dual-batch
// interleave (spill). Bound = 40 serial barrier-locked reduction phases
// (u<->v dependency) x ~750ns at hard 1-block/CU occupancy.
//
// Scaled exp-domain state (A = 2^{alpha*log2e}, Cs = 2^8/A):
//   EU_i  = 1/(sum_j es_ij*EV_j + A*evd)         es = 2^{s*log2e} (f16)
//   eud_s = Cs/(sum_j EV_j + evd)
//   EV_j  = 1/(sum_i es_ij*EU_i + A*eud_s)
//   evd'  = Cs/(sum_i EU_i + eud_s)
//   Z core = (log2 es + log2 EU + log2 EV)*ln2   (dustbins use alpha2)
//
// Fragment maps (HW-verified v8..v17): wave w, lane l = l15 + 16g:
//   esA[s][j] = es[16w+l15][s*32+g*8+j]   (A operand, row strip)
//   esB[s][j] = es[s*32+g*8+j][16w+l15]   (B operand, col strip)
// C/D layout: col=lane&15, row=(lane>>4)*4+reg (HW-measured).

typedef _Float16 half8 __attribute__((ext_vector_type(8)));
typedef float floatx4 __attribute__((ext_vector_type(4)));

constexpr float L2E = 1.4426950408889634f;
constexpr float LN2 = 0.6931471805599453f;

__device__ __forceinline__ float flog2(float x) { return __builtin_amdgcn_logf(x); }
__device__ __forceinline__ float fexp2(float x) { return __builtin_amdgcn_exp2f(x); }

// 1/d via v_rcp_f32 + one Newton step (<=1 ulp, d>0)
__device__ __forceinline__ float rcp_nr(float d) {
    float r = __builtin_amdgcn_rcpf(d);
    return r * fmaf(-d, r, 2.0f);
}

template <int CTRL>
__device__ __forceinline__ float dpp_add(float x) {
    int y = __builtin_amdgcn_update_dpp(0, __builtin_bit_cast(int, x), CTRL, 0xF, 0xF, true);
    return x + __builtin_bit_cast(float, y);
}
// sum over the 16 lanes of each row (lanes l&15)
__device__ __forceinline__ float reduce16(float x) {
    x = dpp_add<0xB1>(x);    // xor 1
    x = dpp_add<0x4E>(x);    // xor 2
    x = dpp_add<0x124>(x);   // row_ror:4
    x = dpp_add<0x128>(x);   // row_ror:8
    return x;
}
__device__ __forceinline__ float xor16_add(float x) {
    int y = __builtin_amdgcn_ds_swizzle(__builtin_bit_cast(int, x), 0x401F);
    return x + __builtin_bit_cast(float, y);
}

// esT addressing: col-major, stride 264 shorts, XOR swizzle + g-group pad.
__device__ __forceinline__ int eidx(int col, int r) {
    return col * 264 + ((r ^ ((col & 7) << 3)) + (((col >> 3) & 1) << 3));
}

__global__ __launch_bounds__(1024)
__attribute__((amdgpu_waves_per_eu(4, 4)))
void sinkhorn_kernel(const float* __restrict__ scores,
                     const float* __restrict__ alpha_p,
                     const int* __restrict__ iters_p,
                     float* __restrict__ out)
{
    const int bat = blockIdx.x;
    const int t   = threadIdx.x;
    const int a   = t >> 5;         // prologue/epilogue: rows [8a, 8a+8)
    const int bb  = t & 31;         // prologue/epilogue: cols 4bb.. / 128+4bb..
    const int w   = t >> 6;         // wave 0..15
    const int l   = t & 63;
    const int g   = (t >> 4) & 3;   // k-group within wave
    const int l15 = t & 15;

    const float alpha2 = alpha_p[0] * L2E;
    const float A  = fexp2(alpha2);
    const float Cs = fexp2(8.0f - alpha2);   // 2^8 / A
    const int iters = iters_p[0];

    __shared__ __align__(16) unsigned short esT[256 * 264];  // 132 KB col-major
    __shared__ __align__(16) unsigned short EUa[272];
    __shared__ __align__(16) unsigned short EVa[272];
    __shared__ __align__(16) float wsU[16];
    __shared__ __align__(16) float wsV[16];

    // ---------------- prologue: load scores -> f16 es^T ----------------
    {
        const float* sp = scores + ((size_t)bat << 16) + ((size_t)a << 11) + (bb << 2);
        half8 cp[8];  // per-column packs of this thread's 8 rows
        #pragma unroll
        for (int r = 0; r < 8; ++r) {
            const float4 x0 = *reinterpret_cast<const float4*>(sp + (r << 8));
            const float4 x1 = *reinterpret_cast<const float4*>(sp + (r << 8) + 128);
            cp[0][r] = (_Float16)fexp2(x0.x * L2E);
            cp[1][r] = (_Float16)fexp2(x0.y * L2E);
            cp[2][r] = (_Float16)fexp2(x0.z * L2E);
            cp[3][r] = (_Float16)fexp2(x0.w * L2E);
            cp[4][r] = (_Float16)fexp2(x1.x * L2E);
            cp[5][r] = (_Float16)fexp2(x1.y * L2E);
            cp[6][r] = (_Float16)fexp2(x1.z * L2E);
            cp[7][r] = (_Float16)fexp2(x1.w * L2E);
        }
        #pragma unroll
        for (int ci = 0; ci < 8; ++ci) {
            const int col = (ci < 4) ? ((bb << 2) + ci) : (128 + (bb << 2) + ci - 4);
            *reinterpret_cast<half8*>(&esT[eidx(col, a << 3)]) = cp[ci];
        }
    }
    if (t < 256) EVa[t] = 0x3C00;      // EV = 1.0 (f16)
    if (t < 16)  wsV[t] = 16.0f;       // per-wave sum of 16 ones
    __syncthreads();

    // ---- persistent A-fragments: es row strip of wave w (asm-pinned) ----
    half8 esA[8];
    {
        const int m16 = (w << 4) + l15;
        #pragma unroll
        for (int s = 0; s < 8; ++s) {
            #pragma unroll
            for (int j = 0; j < 8; ++j) {
                const int col = (s << 5) + (g << 3) + j;
                esA[s][j] = __builtin_bit_cast(_Float16, esT[eidx(col, m16)]);
            }
            asm volatile("" : "+v"(esA[s]));  // opaque def: no remat
        }
    }
    // ---- persistent B-fragments: es col strip ----
    half8 esB[8];
    {
        const int colL = (w << 4) + l15;
        #pragma unroll
        for (int s = 0; s < 8; ++s) {
            esB[s] = *reinterpret_cast<const half8*>(
                &esT[eidx(colL, (s << 5) + (g << 3))]);
            asm volatile("" : "+v"(esB[s]));
        }
    }

    float evd = 1.0f, eud_s = 1.0f;

    const half8* evp = reinterpret_cast<const half8*>(EVa) + g;
    const half8* eup = reinterpret_cast<const half8*>(EUa) + g;

    for (int it = 0; it < iters; ++it) {
        // ---- scalars: eud_s from Sum(EV) + evd (all threads, redundant) ----
        float sv = evd;
        {
            const floatx4* wv = reinterpret_cast<const floatx4*>(wsV);
            floatx4 s0 = wv[0], s1 = wv[1], s2 = wv[2], s3 = wv[3];
            floatx4 ss = (s0 + s1) + (s2 + s3);
            sv += (ss[0] + ss[1]) + (ss[2] + ss[3]);
        }
        eud_s = Cs * rcp_nr(sv);
        const float tdu = A * eud_s;
        const float tdv = A * evd;

        // ---- p-phase: D[m][*] = sum_k es[m][k]*EV[k] (2x4 indep chains) ----
        floatx4 acc0 = {0.f, 0.f, 0.f, 0.f}, acc1 = {0.f, 0.f, 0.f, 0.f};
        #pragma unroll
        for (int s = 0; s < 4; ++s) {
            acc0 = __builtin_amdgcn_mfma_f32_16x16x32_f16(esA[2*s],   evp[(2*s) << 2],   acc0, 0, 0, 0);
            acc1 = __builtin_amdgcn_mfma_f32_16x16x32_f16(esA[2*s+1], evp[(2*s+1) << 2], acc1, 0, 0, 0);
        }
        floatx4 acc = acc0 + acc1;

        const float E0 = rcp_nr(acc[0] + tdv);
        const float E1 = rcp_nr(acc[1] + tdv);
        const float E2 = rcp_nr(acc[2] + tdv);
        const float E3 = rcp_nr(acc[3] + tdv);
        if (l15 < 4) {  // rows 16w + 4g + l15
            const float lo  = (l15 & 1) ? E1 : E0;
            const float hi  = (l15 & 1) ? E3 : E2;
            const float val = (l15 & 2) ? hi : lo;
            EUa[(w << 4) + (g << 2) + l15] =
                __builtin_bit_cast(unsigned short, (_Float16)val);
        }
        float sU = (E0 + E1) + (E2 + E3);
        sU = xor16_add(sU);
        sU += __shfl_xor(sU, 32, 64);
        if (l == 0) wsU[w] = sU;
        __syncthreads();

        // ---- scalars: evd' from Sum(EU) + eud_s ----
        float su = eud_s;
        {
            const floatx4* wu = reinterpret_cast<const floatx4*>(wsU);
            floatx4 s0 = wu[0], s1 = wu[1], s2 = wu[2], s3 = wu[3];
            floatx4 ss = (s0 + s1) + (s2 + s3);
            su += (ss[0] + ss[1]) + (ss[2] + ss[3]);
        }
        evd = Cs * rcp_nr(su);

        // ---- q-phase: D[*][n] = sum_k EU[k]*es[k][n] (2x4 indep chains) ----
        floatx4 q0 = {0.f, 0.f, 0.f, 0.f}, q1 = {0.f, 0.f, 0.f, 0.f};
        #pragma unroll
        for (int s = 0; s < 4; ++s) {
            q0 = __builtin_amdgcn_mfma_f32_16x16x32_f16(eup[(2*s) << 2],   esB[2*s],   q0, 0, 0, 0);
            q1 = __builtin_amdgcn_mfma_f32_16x16x32_f16(eup[(2*s+1) << 2], esB[2*s+1], q1, 0, 0, 0);
        }
        floatx4 acc2 = q0 + q1;

        const float EVv = rcp_nr(acc2[0] + tdu);   // col 16w+l15 (rows replicated)
        if (l < 16) EVa[(w << 4) + l] =
            __builtin_bit_cast(unsigned short, (_Float16)EVv);
        float sV = reduce16(EVv);
        if (l == 0) wsV[w] = sV;
        __syncthreads();
    }

    // ---------------- output: Z = (s' + u' + v')*ln2 ----------------
    const float vdust = flog2(evd);
    const float udust = flog2(eud_s);
    float Up[8], Vp[8];
    int cols[8];
    #pragma unroll
    for (int r = 0; r < 8; ++r)
        Up[r] = flog2((float)__builtin_bit_cast(_Float16, EUa[(a << 3) + r]));
    #pragma unroll
    for (int ci = 0; ci < 8; ++ci) {
        cols[ci] = (ci < 4) ? ((bb << 2) + ci) : (128 + (bb << 2) + ci - 4);
        Vp[ci] = flog2((float)__builtin_bit_cast(_Float16, EVa[cols[ci]]));
    }
    const size_t ob = (size_t)bat * 66049;  // 257*257
    #pragma unroll
    for (int ci = 0; ci < 8; ++ci) {
        const int col = cols[ci];
        const half8 esc = *reinterpret_cast<const half8*>(&esT[eidx(col, a << 3)]);
        #pragma unroll
        for (int r = 0; r < 8; ++r) {
            out[ob + (size_t)((a << 3) + r) * 257 + col] =
                (flog2((float)esc[r]) + Up[r] + Vp[ci]) * LN2;
        }
    }
    if (bb == 0) {
        #pragma unroll
        for (int r = 0; r < 8; ++r)
            out[ob + (size_t)((a << 3) + r) * 257 + 256] =
                (alpha2 + Up[r] + vdust) * LN2;
    }
    if (t < 257) {
        const float vp = (t < 256)
            ? flog2((float)__builtin_bit_cast(_Float16, EVa[t])) : vdust;
        out[ob + 65792 + t] = (alpha2 + udust + vp) * LN2;
    }
}

extern "C" void kernel_launch(void* const* d_in, const int* in_sizes, int n_in,
                              void* d_out, int out_size, void* d_ws, size_t ws_size,
                              hipStream_t stream)
{
    const float* scores = (const float*)d_in[0];
    const float* alpha  = (const float*)d_in[1];
    const int*   iters  = (const int*)d_in[2];
    float* out = (float*)d_out;
    const int B = in_sizes[0] >> 16;
    hipLaunchKernelGGL(sinkhorn_kernel, dim3(B), dim3(1024), 0, stream,
                       scores, alpha, iters, out);
}